// Round 4
// baseline (437.830 us; speedup 1.0000x reference)
//
#include <hip/hip_runtime.h>

// SNN LIF scan: T=1024, B=32, N=2048. EXACT sequential-in-T (spikes are
// binary -> trajectory must be bit-exact -> no T-parallelization, R2).
// One thread per (b,n). KEY FIX vs R3: __launch_bounds__(256, 1).
// R1/R3 showed VGPR_Count=32 -- the compiler register-minimized for an
// occupancy this grid can never reach (only 1024 waves exist = 1 wave/SIMD)
// and sank the prefetch loads next to their uses, exposing memory latency
// every step. With min-waves-per-EU=1 the register budget is ~512, so the
// 2x32-deep ping-pong load pipeline stays in registers: one exposed latency
// per 32 steps.
// d_out layout: spikes[T*B*N] ++ v_final[B*N] ++ i_final[B*N].

#define TT 1024
#define BN 65536          // B*N = 32*2048
#define U  32             // batch size per pipeline phase (2 phases in flight)

__global__ __launch_bounds__(256, 1) void snn_lif_kernel(
    const float* __restrict__ x,   // [T, B, N] flat
    float* __restrict__ out)       // spikes ++ v_f ++ i_f
{
    const int idx = blockIdx.x * 256 + threadIdx.x;   // 0..BN-1
    const float* __restrict__ xp = x + idx;
    float* __restrict__ sp = out + idx;

    float v = 0.0f;
    float i = 0.0f;

    const float c_mem = 0.1f;   // fp32(DT*TAU_MEM_INV)
    const float c_syn = 0.8f;   // fp32(1 - DT*TAU_SYN_INV)

    float xa[U], xb[U];

    // Prologue: batch A in flight.
    #pragma unroll
    for (int k = 0; k < U; ++k)
        xa[k] = xp[(size_t)k * BN];

    #pragma unroll 1
    for (int t0 = 0; t0 < TT; t0 += 2 * U) {
        // Batch B issued before batch A is consumed: B's 32 loads are in
        // flight behind A's compute.
        #pragma unroll
        for (int k = 0; k < U; ++k)
            xb[k] = xp[(size_t)(t0 + U + k) * BN];

        #pragma unroll
        for (int k = 0; k < U; ++k) {
            // Exact ref op sequence; _rn intrinsics forbid FMA contraction
            // (spike decisions are binary -- must match fp32 ref bit-exactly).
            float dv    = __fmul_rn(c_mem, __fadd_rn(__fsub_rn(0.0f, v), i));
            float v_dec = __fadd_rn(v, dv);
            float i_dec = __fmul_rn(i, c_syn);
            bool fired  = (v_dec > 1.0f);
            v = fired ? 0.0f : v_dec;
            i = __fadd_rn(i_dec, xa[k]);
            __builtin_nontemporal_store(fired ? 1.0f : 0.0f,
                                        &sp[(size_t)(t0 + k) * BN]);
        }

        // Refill batch A for the next outer iteration (uniform branch).
        if (t0 + 2 * U < TT) {
            #pragma unroll
            for (int k = 0; k < U; ++k)
                xa[k] = xp[(size_t)(t0 + 2 * U + k) * BN];
        }

        #pragma unroll
        for (int k = 0; k < U; ++k) {
            float dv    = __fmul_rn(c_mem, __fadd_rn(__fsub_rn(0.0f, v), i));
            float v_dec = __fadd_rn(v, dv);
            float i_dec = __fmul_rn(i, c_syn);
            bool fired  = (v_dec > 1.0f);
            v = fired ? 0.0f : v_dec;
            i = __fadd_rn(i_dec, xb[k]);
            __builtin_nontemporal_store(fired ? 1.0f : 0.0f,
                                        &sp[(size_t)(t0 + U + k) * BN]);
        }
    }

    out[(size_t)TT * BN + idx]      = v;
    out[(size_t)TT * BN + BN + idx] = i;
}

extern "C" void kernel_launch(void* const* d_in, const int* in_sizes, int n_in,
                              void* d_out, int out_size, void* d_ws, size_t ws_size,
                              hipStream_t stream) {
    const float* x = (const float*)d_in[0];
    float* out = (float*)d_out;
    snn_lif_kernel<<<BN / 256, 256, 0, stream>>>(x, out);
}

// Round 5
// 423.299 us; speedup vs baseline: 1.0343x; 1.0343x over previous
//
#include <hip/hip_runtime.h>

// SNN LIF scan: T=1024, B=32, N=2048. EXACT sequential-in-T (spikes are
// binary -> trajectory must be bit-exact -> no T-parallelization, R2).
// R5: one thread per TWO adjacent neurons, float2 loads AND float2 spike
// stores. Rationale: vmcnt counts loads+stores with in-order completion, so
// R3/R4's per-element scalar stores sat between prefetch loads in issue
// order and made every load-wait transitively wait on store acks. float2
// halves the vmem op count (same bytes), doubles bytes-in-flight per
// outstanding op, and gives 2-way per-thread ILP. 256 blocks x 128 thr
// -> 1 block/CU, 2 waves/CU.
// d_out layout: spikes[T*B*N] ++ v_final[B*N] ++ i_final[B*N].

#define TT 1024
#define BN 65536           // B*N
#define BN2 (BN / 2)       // stride per timestep in float2 units
#define U  16              // float2 batch per pipeline phase (2 phases)

__global__ __launch_bounds__(128, 1) void snn_lif_kernel(
    const float* __restrict__ xf,
    float* __restrict__ outf)
{
    const int idx = blockIdx.x * 128 + threadIdx.x;       // 0..BN2-1
    const float2* __restrict__ xp = (const float2*)xf + idx;
    float2* __restrict__ sp = (float2*)outf + idx;

    float v0 = 0.0f, v1 = 0.0f;
    float i0 = 0.0f, i1 = 0.0f;

    const float c_mem = 0.1f;   // fp32(DT*TAU_MEM_INV)
    const float c_syn = 0.8f;   // fp32(1 - DT*TAU_SYN_INV)

    // One LIF step for one neuron. Exact ref op sequence; _rn intrinsics
    // forbid FMA contraction (spike decisions are binary -- must match the
    // fp32 reference bit-exactly; this is load-bearing, do not touch).
    auto step = [&](float& v, float& i, float xin) -> float {
        float dv    = __fmul_rn(c_mem, __fadd_rn(__fsub_rn(0.0f, v), i));
        float v_dec = __fadd_rn(v, dv);
        float i_dec = __fmul_rn(i, c_syn);
        bool fired  = (v_dec > 1.0f);
        v = fired ? 0.0f : v_dec;
        i = __fadd_rn(i_dec, xin);
        return fired ? 1.0f : 0.0f;
    };

    float2 xa[U], xb[U];

    // Prologue: batch A in flight.
    #pragma unroll
    for (int k = 0; k < U; ++k)
        xa[k] = xp[(size_t)k * BN2];

    #pragma unroll 1
    for (int t0 = 0; t0 < TT; t0 += 2 * U) {
        // Issue batch B before consuming batch A.
        #pragma unroll
        for (int k = 0; k < U; ++k)
            xb[k] = xp[(size_t)(t0 + U + k) * BN2];

        #pragma unroll
        for (int k = 0; k < U; ++k) {
            float2 z;
            z.x = step(v0, i0, xa[k].x);
            z.y = step(v1, i1, xa[k].y);
            sp[(size_t)(t0 + k) * BN2] = z;
        }

        // Refill batch A for the next outer iteration (uniform branch).
        if (t0 + 2 * U < TT) {
            #pragma unroll
            for (int k = 0; k < U; ++k)
                xa[k] = xp[(size_t)(t0 + 2 * U + k) * BN2];
        }

        #pragma unroll
        for (int k = 0; k < U; ++k) {
            float2 z;
            z.x = step(v0, i0, xb[k].x);
            z.y = step(v1, i1, xb[k].y);
            sp[(size_t)(t0 + U + k) * BN2] = z;
        }
    }

    // Final state (float2 contiguous in both v and i regions).
    float2* vf = (float2*)(outf + (size_t)TT * BN) + idx;
    float2* iff = (float2*)(outf + (size_t)TT * BN + BN) + idx;
    *vf = make_float2(v0, v1);
    *iff = make_float2(i0, i1);
}

extern "C" void kernel_launch(void* const* d_in, const int* in_sizes, int n_in,
                              void* d_out, int out_size, void* d_ws, size_t ws_size,
                              hipStream_t stream) {
    const float* x = (const float*)d_in[0];
    float* out = (float*)d_out;
    // BN2 = 32768 threads -> 256 blocks of 128 -> 1 block/CU, 2 waves/CU.
    snn_lif_kernel<<<BN2 / 128, 128, 0, stream>>>(x, out);
}